// Round 3
// baseline (496.876 us; speedup 1.0000x reference)
//
#include <hip/hip_runtime.h>
#include <hip/hip_bf16.h>

// MLA forward, bf16-MFMA pipeline. B=2 S=2048 DIM=2048 H=16 DH=128 LQ=1024 LKV=512
// R13: gemm8 — 256x256 tile, 8 waves, BK=32, 4-deep LDS ring (128KB), counted
// vmcnt(8) (never 0 in steady state), 1 barrier + 32 MFMA/wave per K-tile
// (AITER K-loop shape). Used for the two biggest GEMMs; k|v + output GEMM stay
// on the 128^2 path. Flash v9 unchanged (R12 post-mortem: staging latency was
// already TLP-hidden; flash is near its LDS floor).

#define Bb 2
#define Ss 2048
#define DIMd 2048
#define Hh 16
#define DHd 128

typedef __hip_bfloat16 bf16;
typedef __attribute__((ext_vector_type(8))) short short8;
typedef __attribute__((ext_vector_type(4))) float floatx4;
typedef __attribute__((ext_vector_type(16))) float floatx16;
typedef __attribute__((ext_vector_type(2))) unsigned int uintx2;

#define MFMA(a, b, c) __builtin_amdgcn_mfma_f32_16x16x32_bf16((a), (b), (c), 0, 0, 0)
#define MFMA32(a, b, c) __builtin_amdgcn_mfma_f32_32x32x16_bf16((a), (b), (c), 0, 0, 0)

__device__ __forceinline__ void async16(const bf16* g, bf16* l) {
  __builtin_amdgcn_global_load_lds(
      (const __attribute__((address_space(1))) unsigned int*)g,
      (__attribute__((address_space(3))) unsigned int*)l, 16, 0, 0);
}

// ---------------- fused f32 -> bf16 convert of all 9 tensors ----------------
__global__ __launch_bounds__(256) void cvt_all(
    const float* x, const float* wlq, const float* wlkv, const float* wq,
    const float* wqr, const float* wk, const float* wv, const float* wkr,
    const float* wo, bf16* dx, bf16* dwlq, bf16* dwlkv, bf16* dwq, bf16* dwqr,
    bf16* dwk, bf16* dwv, bf16* dwkr, bf16* dwo) {
  long i = (long)blockIdx.x * 256 + threadIdx.x;
  const float* src;
  bf16* dst;
  long base;
  if (i < 2097152L)      { src = x;    dst = dx;    base = 0; }
  else if (i < 2621440L) { src = wlq;  dst = dwlq;  base = 2097152L; }
  else if (i < 2883584L) { src = wlkv; dst = dwlkv; base = 2621440L; }
  else if (i < 3407872L) { src = wq;   dst = dwq;   base = 2883584L; }
  else if (i < 3932160L) { src = wqr;  dst = dwqr;  base = 3407872L; }
  else if (i < 4194304L) { src = wk;   dst = dwk;   base = 3932160L; }
  else if (i < 4456448L) { src = wv;   dst = dwv;   base = 4194304L; }
  else if (i < 5505024L) { src = wkr;  dst = dwkr;  base = 4456448L; }
  else                   { src = wo;   dst = dwo;   base = 5505024L; }
  long j = i - base;
  float4 f = ((const float4*)src)[j];
  union { ushort4 u4; bf16 h[4]; } cv;
  cv.h[0] = __float2bfloat16(f.x);
  cv.h[1] = __float2bfloat16(f.y);
  cv.h[2] = __float2bfloat16(f.z);
  cv.h[3] = __float2bfloat16(f.w);
  ((ushort4*)dst)[j] = cv.u4;
}

// ---------------- GEMM body: C = A @ B^T, 128x128 tile, BK=64 ----------------
template <int MODE>
__device__ __forceinline__ void gemm_body(const bf16* __restrict__ A,
                                          const bf16* __restrict__ Bw,
                                          const float* __restrict__ bias,
                                          void* __restrict__ Cout,
                                          void* __restrict__ Cout2,
                                          const float* __restrict__ fco,
                                          const float* __restrict__ fsi,
                                          int M, int N, int K, int lda) {
  extern __shared__ __align__(16) bf16 smem[];  // 128*129
  bf16* As = smem;
  bf16* Bs = smem + 8192;
  const int tid = threadIdx.x;
  const int lane = tid & 63;
  const int w = tid >> 6;
  const int wm = w & 1, wn = w >> 1;
  const int m0 = blockIdx.y * 128, n0 = blockIdx.x * 128;
  const int lr = lane & 15, lg = lane >> 4;

  floatx4 acc[4][4];
#pragma unroll
  for (int mi = 0; mi < 4; ++mi)
#pragma unroll
    for (int ni = 0; ni < 4; ++ni)
#pragma unroll
      for (int r = 0; r < 4; ++r) acc[mi][ni][r] = 0.f;

  for (int k0 = 0; k0 < K; k0 += 64) {
    __syncthreads();
#pragma unroll
    for (int i = 0; i < 4; ++i) {
      int c = i * 256 + tid;
      int row = c >> 3;
      int cg = (c & 7) ^ (row & 7);
      async16(A + (size_t)(m0 + row) * lda + k0 + cg * 8, As + (i * 256 + w * 64) * 8);
      async16(Bw + (size_t)(n0 + row) * K + k0 + cg * 8, Bs + (i * 256 + w * 64) * 8);
    }
    __syncthreads();

#pragma unroll
    for (int ks = 0; ks < 2; ++ks) {
      short8 af[4], bfr[4];
#pragma unroll
      for (int mi = 0; mi < 4; ++mi) {
        int row = wm * 64 + mi * 16 + lr;
        af[mi] = *(const short8*)&As[row * 64 + (((ks * 4 + lg) ^ (lr & 7)) * 8)];
      }
#pragma unroll
      for (int ni = 0; ni < 4; ++ni) {
        int row = wn * 64 + ni * 16 + lr;
        bfr[ni] = *(const short8*)&Bs[row * 64 + (((ks * 4 + lg) ^ (lr & 7)) * 8)];
      }
#pragma unroll
      for (int mi = 0; mi < 4; ++mi)
#pragma unroll
        for (int ni = 0; ni < 4; ++ni)
          acc[mi][ni] = MFMA(af[mi], bfr[ni], acc[mi][ni]);
    }
  }

  if (MODE == 5 && n0 >= 2048) {
    __syncthreads();
#pragma unroll
    for (int mi = 0; mi < 4; ++mi)
#pragma unroll
      for (int ni = 0; ni < 4; ++ni)
#pragma unroll
        for (int r = 0; r < 4; ++r) {
          int ml = wm * 64 + mi * 16 + lg * 4 + r;
          int nl = wn * 64 + ni * 16 + lr;
          smem[ml * 129 + nl] = __float2bfloat16(acc[mi][ni][r]);
        }
    __syncthreads();
    int bb = m0 >> 11, s0 = m0 & 2047;
    int hh = (n0 - 2048) >> 7;
    short* vbase = (short*)Cout2 + ((size_t)(bb * Hh + hh) * 128) * Ss;
#pragma unroll
    for (int pa = 0; pa < 8; ++pa) {
      int d = pa * 16 + (tid >> 4);
      int sc = (tid & 15) * 8;
      short8 v;
#pragma unroll
      for (int i = 0; i < 8; ++i) v[i] = *(const short*)&smem[(sc + i) * 129 + d];
      *(short8*)(vbase + (size_t)d * Ss + s0 + sc) = v;
    }
    return;
  }

#pragma unroll
  for (int mi = 0; mi < 4; ++mi)
#pragma unroll
    for (int ni = 0; ni < 4; ++ni)
#pragma unroll
      for (int r = 0; r < 4; ++r) {
        int m = m0 + wm * 64 + mi * 16 + lg * 4 + r;
        int n = n0 + wn * 64 + ni * 16 + lr;
        float v = acc[mi][ni][r];
        int bb = m >> 11, s = m & 2047;
        if (MODE == 3) {
          v += bias[n];
          ((float*)Cout)[(size_t)m * N + n] = v;
        } else if (MODE == 4) {
          if (n < 2048) {
            int hh = n >> 7, d = n & 127;
            ((bf16*)Cout)[((size_t)((bb * Hh + hh) * Ss + s)) * 256 + d] =
                __float2bfloat16(v);
          } else {
            int n2 = n - 2048;
            int hh = n2 >> 7, d = n2 & 127;
            v += bias[n2];
            float vp = __shfl_xor(v, 1, 64);
            float co = fco[s * 64 + (d >> 1)];
            float sn = fsi[s * 64 + (d >> 1)];
            v = (d & 1) ? (v * co + vp * sn) : (v * co - vp * sn);
            ((bf16*)Cout)[((size_t)((bb * Hh + hh) * Ss + s)) * 256 + 128 + d] =
                __float2bfloat16(v);
          }
        } else if (MODE == 5) {
          int hh = n >> 7, d = n & 127;
          ((bf16*)Cout)[((size_t)((bb * Hh + hh) * Ss + s)) * 256 + d] =
              __float2bfloat16(v);
        } else if (MODE == 6) {
          if (n < 1536) {
            ((bf16*)Cout)[(size_t)m * 1536 + n] = __float2bfloat16(v);
          } else {
            int n2 = n - 1536;
            int hh = n2 >> 7, d = n2 & 127;
            v += bias[n2];
            float vp = __shfl_xor(v, 1, 64);
            float co = fco[s * 64 + (d >> 1)];
            float sn = fsi[s * 64 + (d >> 1)];
            v = (d & 1) ? (v * co + vp * sn) : (v * co - vp * sn);
            ((bf16*)Cout2)[((size_t)((bb * Hh + hh) * Ss + s)) * 256 + 128 + d] =
                __float2bfloat16(v);
          }
        }
      }
}

template <int MODE>
__global__ __launch_bounds__(256, 4) void gemm_bt(const bf16* __restrict__ A,
                                                  const bf16* __restrict__ Bw,
                                                  const float* __restrict__ bias,
                                                  void* __restrict__ Cout,
                                                  void* __restrict__ Cout2,
                                                  const float* __restrict__ fco,
                                                  const float* __restrict__ fsi,
                                                  int M, int N, int K, int lda) {
  gemm_body<MODE>(A, Bw, bias, Cout, Cout2, fco, fsi, M, N, K, lda);
}

// ---------------- gemm8: C = A @ B^T, 256x256 tile, BK=32, 4-deep ring -------
// 8 waves (512 thr): wm = w>>2 (2 M-halves), wn = w&3 (4 N-quarters); per-wave
// C = 128x64 = 8x4 fragments. Per K-tile: 12 ds_read_b128 + 32 MFMA per wave,
// ONE s_barrier, steady-state s_waitcnt vmcnt(8) (tile t gated, t+1/t+2 still
// in flight, t+3 staged after the barrier into the buffer freed by it).
// LDS [256][32] rows are 64B -> frag reads spread banks via cg = lg^((row>>1)&3)
// pre-applied on the global source (linear LDS dest, required by gload_lds).
#define G8_STAGE(TT)                                                           \
  {                                                                            \
    bf16* db = smem + ((TT) & 3) * 16384;                                      \
    const int kk0 = (TT) * 32;                                                 \
    _Pragma("unroll") for (int i = 0; i < 2; ++i) {                            \
      int c = i * 512 + tid;                                                   \
      int row = c >> 2;                                                        \
      int cg = (c & 3) ^ ((row >> 1) & 3);                                     \
      async16(A + (size_t)(m0 + row) * lda + kk0 + cg * 8, db + c * 8);        \
    }                                                                          \
    _Pragma("unroll") for (int i = 0; i < 2; ++i) {                            \
      int c = i * 512 + tid;                                                   \
      int row = c >> 2;                                                        \
      int cg = (c & 3) ^ ((row >> 1) & 3);                                     \
      async16(Bw + (size_t)(n0 + row) * KTOT + kk0 + cg * 8,                   \
              db + 8192 + c * 8);                                              \
    }                                                                          \
  }

#define G8_COMPUTE(TT)                                                         \
  {                                                                            \
    const bf16* cb = smem + ((TT) & 3) * 16384;                                \
    short8 bfr[4];                                                             \
    _Pragma("unroll") for (int ni = 0; ni < 4; ++ni) {                         \
      int row = wn * 64 + ni * 16 + lr;                                        \
      bfr[ni] = *(const short8*)&cb[8192 + row * 32 +                          \
                                    ((lg ^ ((row >> 1) & 3)) * 8)];            \
    }                                                                          \
    short8 af[8];                                                              \
    _Pragma("unroll") for (int mi = 0; mi < 8; ++mi) {                         \
      int row = wm * 128 + mi * 16 + lr;                                       \
      af[mi] = *(const short8*)&cb[row * 32 + ((lg ^ ((row >> 1) & 3)) * 8)];  \
    }                                                                          \
    __builtin_amdgcn_s_setprio(1);                                             \
    _Pragma("unroll") for (int mi = 0; mi < 8; ++mi)                           \
      _Pragma("unroll") for (int ni = 0; ni < 4; ++ni)                         \
          acc[mi][ni] = MFMA(af[mi], bfr[ni], acc[mi][ni]);                    \
    __builtin_amdgcn_s_setprio(0);                                             \
  }

template <int MODE, int KTOT>
__global__ __launch_bounds__(512, 2) void gemm8(const bf16* __restrict__ A,
                                                const bf16* __restrict__ Bw,
                                                const float* __restrict__ bias,
                                                void* __restrict__ Cout,
                                                void* __restrict__ Cout2,
                                                const float* __restrict__ fco,
                                                const float* __restrict__ fsi,
                                                int M, int N, int lda) {
  extern __shared__ __align__(16) bf16 smem[];  // 4 bufs x (A 8192 | B 8192)
  constexpr int NT = KTOT / 32;
  const int tid = threadIdx.x;
  const int lane = tid & 63;
  const int w = tid >> 6;
  const int wm = w >> 2, wn = w & 3;
  const int m0 = blockIdx.y * 256, n0 = blockIdx.x * 256;
  const int lr = lane & 15, lg = lane >> 4;

  floatx4 acc[8][4];
#pragma unroll
  for (int mi = 0; mi < 8; ++mi)
#pragma unroll
    for (int ni = 0; ni < 4; ++ni)
#pragma unroll
      for (int r = 0; r < 4; ++r) acc[mi][ni][r] = 0.f;

  G8_STAGE(0);
  G8_STAGE(1);
  G8_STAGE(2);

#pragma unroll 1
  for (int t = 0; t < NT - 2; ++t) {
    asm volatile("s_waitcnt vmcnt(8)" ::: "memory");
    __builtin_amdgcn_s_barrier();
    if (t < NT - 3) G8_STAGE(t + 3);
    G8_COMPUTE(t);
  }
  asm volatile("s_waitcnt vmcnt(4)" ::: "memory");
  __builtin_amdgcn_s_barrier();
  G8_COMPUTE(NT - 2);
  asm volatile("s_waitcnt vmcnt(0)" ::: "memory");
  __builtin_amdgcn_s_barrier();
  G8_COMPUTE(NT - 1);

#pragma unroll
  for (int mi = 0; mi < 8; ++mi)
#pragma unroll
    for (int ni = 0; ni < 4; ++ni)
#pragma unroll
      for (int r = 0; r < 4; ++r) {
        int m = m0 + wm * 128 + mi * 16 + lg * 4 + r;
        int n = n0 + wn * 64 + ni * 16 + lr;
        float v = acc[mi][ni][r];
        int bb = m >> 11, s = m & 2047;
        if (MODE == 4) {
          if (n < 2048) {
            int hh = n >> 7, d = n & 127;
            ((bf16*)Cout)[((size_t)((bb * Hh + hh) * Ss + s)) * 256 + d] =
                __float2bfloat16(v);
          } else {
            int n2 = n - 2048;
            int hh = n2 >> 7, d = n2 & 127;
            v += bias[n2];
            float vp = __shfl_xor(v, 1, 64);
            float co = fco[s * 64 + (d >> 1)];
            float sn = fsi[s * 64 + (d >> 1)];
            v = (d & 1) ? (v * co + vp * sn) : (v * co - vp * sn);
            ((bf16*)Cout)[((size_t)((bb * Hh + hh) * Ss + s)) * 256 + 128 + d] =
                __float2bfloat16(v);
          }
        } else if (MODE == 6) {
          if (n < 1536) {
            ((bf16*)Cout)[(size_t)m * 1536 + n] = __float2bfloat16(v);
          } else {
            int n2 = n - 1536;
            int hh = n2 >> 7, d = n2 & 127;
            v += bias[n2];
            float vp = __shfl_xor(v, 1, 64);
            float co = fco[s * 64 + (d >> 1)];
            float sn = fsi[s * 64 + (d >> 1)];
            v = (d & 1) ? (v * co + vp * sn) : (v * co - vp * sn);
            ((bf16*)Cout2)[((size_t)((bb * Hh + hh) * Ss + s)) * 256 + 128 + d] =
                __float2bfloat16(v);
          }
        }
      }
}

// ---------------- flash attention v9 (unchanged from R12) ----------------
#define FA_STAGE(KSN, VSN, J)                                                    \
  {                                                                              \
    _Pragma("unroll") for (int i = 0; i < 4; ++i) {                              \
      int r = w * 8 + i * 2 + (lane >> 5);                                       \
      async16(Kb + (size_t)((J) + r) * 256 + (((lane & 31) ^ (r & 7)) * 8),      \
              KSN + (w * 8 + i * 2) * 256);                                      \
    }                                                                            \
    _Pragma("unroll") for (int i = 0; i < 2; ++i) {                              \
      int d = w * 32 + i * 16 + (lane >> 2);                                     \
      async16(Vb + (size_t)d * Ss + (J) + (((lane & 3) ^ ((d >> 1) & 3)) * 8),   \
              VSN + (w * 32 + i * 16) * 32);                                     \
    }                                                                            \
  }

#define FA_COMPUTE(KP, VQ)                                                       \
  {                                                                              \
    floatx16 sf;                                                                 \
    _Pragma("unroll") for (int r = 0; r < 16; ++r) sf[r] = 0.f;                  \
    __builtin_amdgcn_s_setprio(1);                                               \
    _Pragma("unroll") for (int dt = 0; dt < 16; ++dt) {                          \
      short8 kf = *(const short8*)(KP[dt & 3] + (dt >> 2) * 64);                 \
      sf = MFMA32(kf, qf[dt], sf);                                               \
    }                                                                            \
    __builtin_amdgcn_s_setprio(0);                                               \
    unsigned pk[8];                                                              \
    _Pragma("unroll") for (int rp = 0; rp < 8; ++rp) {                           \
      float p0 = exp2f(sf[2 * rp] * CE);                                         \
      float p1 = exp2f(sf[2 * rp + 1] * CE);                                     \
      l += p0 + p1;                                                              \
      bf16 b0 = __float2bfloat16(p0);                                            \
      bf16 b1 = __float2bfloat16(p1);                                            \
      pk[rp] = ((unsigned)*(const unsigned short*)&b1 << 16) |                   \
               *(const unsigned short*)&b0;                                      \
    }                                                                            \
    __builtin_amdgcn_s_setprio(1);                                               \
    _Pragma("unroll") for (int kb = 0; kb < 2; ++kb) {                           \
      uintx2 w02 = __builtin_amdgcn_permlane32_swap(pk[kb * 4 + 0],              \
                                                    pk[kb * 4 + 2], false, false); \
      uintx2 w13 = __builtin_amdgcn_permlane32_swap(pk[kb * 4 + 1],              \
                                                    pk[kb * 4 + 3], false, false); \
      union { unsigned u[4]; short8 s; } pa;                                     \
      pa.u[0] = w02.x; pa.u[1] = w13.x; pa.u[2] = w02.y; pa.u[3] = w13.y;        \
      _Pragma("unroll") for (int nb = 0; nb < 4; ++nb) {                         \
        short8 vf = *(const short8*)(VQ[kb] + nb * 1024);                        \
        oacc[nb] = MFMA32(pa.s, vf, oacc[nb]);                                   \
      }                                                                          \
    }                                                                            \
    __builtin_amdgcn_s_setprio(0);                                               \
    __syncthreads();                                                             \
  }

__global__ __launch_bounds__(256, 2) void flash_attn(const bf16* __restrict__ Q,
                                                     const bf16* __restrict__ Kc,
                                                     const bf16* __restrict__ Vt,
                                                     bf16* __restrict__ Oa) {
  const float CE = 0.08838834764831845f * 1.4426950408889634f;  // scale*log2e
  __shared__ __align__(16) bf16 Ks0[32 * 256];  // 16KB
  __shared__ __align__(16) bf16 Ks1[32 * 256];  // 16KB
  __shared__ __align__(16) bf16 Vs0[128 * 32];  // 8KB
  __shared__ __align__(16) bf16 Vs1[128 * 32];  // 8KB

  const int lane = threadIdx.x & 63;
  const int w = threadIdx.x >> 6;
  const int m = lane & 31;   // q column / d column / lds row index
  const int hi = lane >> 5;  // k-slice half
  const int bh = blockIdx.x;
  const int b = bh >> 4, h = bh & 15;
  const int q0 = blockIdx.y * 128 + w * 32;

  const bf16* Qb = Q + (size_t)bh * Ss * 256;
  const bf16* Kb = Kc + (size_t)bh * Ss * 256;
  const bf16* Vb = Vt + (size_t)bh * 128 * Ss;

  // Q fragments (B-operand): lane holds Q[q0+m][dt*16 + hi*8 + j]
  short8 qf[16];
  {
    const short* Qrow = (const short*)Qb + (size_t)(q0 + m) * 256 + hi * 8;
#pragma unroll
    for (int dt = 0; dt < 16; ++dt) qf[dt] = *(const short8*)(Qrow + dt * 16);
  }

  // Loop-invariant LDS read pointers, per buffer (static indexing only).
  const int key = m & 7;
  const int vkey = (m >> 1) & 3;
  const short* kp0[4];
  const short* kp1[4];
#pragma unroll
  for (int dl = 0; dl < 4; ++dl) {
    int off = m * 256 + (((2 * dl + hi) ^ key) * 8);
    kp0[dl] = (const short*)Ks0 + off;
    kp1[dl] = (const short*)Ks1 + off;
  }
  const short* vq0[2];
  const short* vq1[2];
#pragma unroll
  for (int kb = 0; kb < 2; ++kb) {
    int off = m * 32 + (((2 * kb + hi) ^ vkey) * 8);
    vq0[kb] = (const short*)Vs0 + off;
    vq1[kb] = (const short*)Vs1 + off;
  }

  float l = 0.f;
  floatx16 oacc[4];
#pragma unroll
  for (int nb = 0; nb < 4; ++nb)
#pragma unroll
    for (int r = 0; r < 16; ++r) oacc[nb][r] = 0.f;

  FA_STAGE(Ks0, Vs0, 0);
  __syncthreads();

#pragma unroll 1
  for (int g = 0; g < 64; g += 2) {
    // body A: stage tile g+1 into buf1, compute tile g from buf0
    FA_STAGE(Ks1, Vs1, (g + 1) * 32);
    FA_COMPUTE(kp0, vq0);
    // body B: stage tile g+2 into buf0 (guarded), compute tile g+1 from buf1
    int jn = (g + 2) * 32;
    if (jn < Ss) FA_STAGE(Ks0, Vs0, jn);
    FA_COMPUTE(kp1, vq1);
  }

  // total l for q = q0+m (both halves hold partials over disjoint k)
  float lsum = l + __shfl_xor(l, 32, 64);
  float inv = 1.f / lsum;

#pragma unroll
  for (int r = 0; r < 16; ++r) {
    int qr = (r & 3) + 8 * (r >> 2) + 4 * hi;        // O row (q-local)
    float invr = __shfl(inv, (lane & 32) + qr, 64);  // inv of that q
    int s = q0 + qr;
#pragma unroll
    for (int nb = 0; nb < 4; ++nb) {
      int d = nb * 32 + m;
      Oa[((size_t)(b * Ss + s)) * (Hh * 128) + h * 128 + d] =
          __float2bfloat16(oacc[nb][r] * invr);
    }
  }
}

// ---------------- host ----------------
extern "C" void kernel_launch(void* const* d_in, const int* in_sizes, int n_in,
                              void* d_out, int out_size, void* d_ws, size_t ws_size,
                              hipStream_t stream) {
  const float* x    = (const float*)d_in[0];
  const float* fco  = (const float*)d_in[1];
  const float* fsi  = (const float*)d_in[2];
  const float* wlq  = (const float*)d_in[3];
  const float* wlkv = (const float*)d_in[4];
  const float* wq   = (const float*)d_in[5];
  const float* wk   = (const float*)d_in[6];
  const float* wv   = (const float*)d_in[7];
  const float* wqr  = (const float*)d_in[8];
  const float* bqr  = (const float*)d_in[9];
  const float* wkr  = (const float*)d_in[10];
  const float* bkr  = (const float*)d_in[11];
  const float* wo   = (const float*)d_in[12];
  const float* bo   = (const float*)d_in[13];

  char* ws = (char*)d_ws;
  size_t o = 0;
  bf16* x_b    = (bf16*)(ws + o); o += (size_t)Bb * Ss * DIMd * 2;
  bf16* wbig   = (bf16*)(ws + o); o += (size_t)3584 * 2048 * 2;   // [wlq;wlkv;wkr]
  bf16* wqcat  = (bf16*)(ws + o); o += (size_t)4096 * 1024 * 2;   // [wq;wqr]
  bf16* wkvcat = (bf16*)(ws + o); o += (size_t)4096 * 512 * 2;    // [wk;wv]
  bf16* wo_b   = (bf16*)(ws + o); o += (size_t)2048 * 2048 * 2;
  bf16* ccat   = (bf16*)(ws + o); o += (size_t)4096 * 1536 * 2;   // [cq|ckv]
  bf16* qcat   = (bf16*)(ws + o); o += (size_t)Bb * Hh * Ss * 256 * 2;
  bf16* kcat   = (bf16*)(ws + o); o += (size_t)Bb * Hh * Ss * 256 * 2;
  bf16* vt     = (bf16*)(ws + o); o += (size_t)Bb * Hh * 128 * Ss * 2;
  bf16* attn   = (bf16*)(ws + o); o += (size_t)4096 * 2048 * 2;

  static bool g8init = false;
  if (!g8init) {
    hipFuncSetAttribute(reinterpret_cast<const void*>(gemm8<6, 2048>),
                        hipFuncAttributeMaxDynamicSharedMemorySize, 131072);
    hipFuncSetAttribute(reinterpret_cast<const void*>(gemm8<4, 1024>),
                        hipFuncAttributeMaxDynamicSharedMemorySize, 131072);
    g8init = true;
  }

  cvt_all<<<25600, 256, 0, stream>>>(
      x, wlq, wlkv, wq, wqr, wk, wv, wkr, wo,
      x_b,
      wbig,
      wbig + (size_t)1024 * 2048,
      wqcat,
      wqcat + (size_t)2048 * 1024,
      wkvcat,
      wkvcat + (size_t)2048 * 512,
      wbig + (size_t)1536 * 2048,
      wo_b);

  const int M = Bb * Ss;  // 4096
  const int GEMM_LDS = 128 * 129 * 2;

  // x -> [cq | ckv | kr(rope)] : 4096 x 3584, K=2048 (256^2 tiles: 14 x 16)
  gemm8<6, 2048><<<dim3(14, 16), 512, 131072, stream>>>(
      x_b, wbig, bkr, ccat, kcat, fco, fsi, M, 3584, 2048);
  // cq -> [q | qr(rope)] : 4096 x 4096, K=1024 (16 x 16)
  gemm8<4, 1024><<<dim3(16, 16), 512, 131072, stream>>>(
      ccat, wqcat, bqr, qcat, nullptr, fco, fsi, M, 4096, 1536);
  // ckv -> [k | v(transposed)] : 4096 x 4096, K=512 (128^2 path, MODE 5)
  gemm_bt<5><<<dim3(32, 32), 256, GEMM_LDS, stream>>>(
      ccat + 1024, wkvcat, nullptr, kcat, vt, nullptr, nullptr, M, 4096, 512, 1536);

  flash_attn<<<dim3(Bb * Hh, Ss / 128), 256, 0, stream>>>(qcat, kcat, vt, attn);

  gemm_bt<3><<<dim3(16, 32), 256, GEMM_LDS, stream>>>(
      attn, wo_b, bo, (float*)d_out, nullptr, nullptr, nullptr, M, 2048, 2048, 2048);
}

// Round 4
// 466.904 us; speedup vs baseline: 1.0642x; 1.0642x over previous
//
#include <hip/hip_runtime.h>
#include <hip/hip_bf16.h>

// MLA forward, bf16-MFMA pipeline. B=2 S=2048 DIM=2048 H=16 DH=128 LQ=1024 LKV=512
// R14: revert gemm8 (1 block/CU killed it: counted-vmcnt without 8-phase
// interleave = null per catalog regime gate). Back to R12's 128^2 GEMMs + NEW
// coalesced epilogue: bf16 modes (4/5/6) stage C through LDS [128][136] and
// store 8x short8 per thread (was 64x scattered 2B stores). Flash v9 unchanged.

#define Bb 2
#define Ss 2048
#define DIMd 2048
#define Hh 16
#define DHd 128

typedef __hip_bfloat16 bf16;
typedef __attribute__((ext_vector_type(8))) short short8;
typedef __attribute__((ext_vector_type(4))) float floatx4;
typedef __attribute__((ext_vector_type(16))) float floatx16;
typedef __attribute__((ext_vector_type(2))) unsigned int uintx2;

#define MFMA(a, b, c) __builtin_amdgcn_mfma_f32_16x16x32_bf16((a), (b), (c), 0, 0, 0)
#define MFMA32(a, b, c) __builtin_amdgcn_mfma_f32_32x32x16_bf16((a), (b), (c), 0, 0, 0)

__device__ __forceinline__ void async16(const bf16* g, bf16* l) {
  __builtin_amdgcn_global_load_lds(
      (const __attribute__((address_space(1))) unsigned int*)g,
      (__attribute__((address_space(3))) unsigned int*)l, 16, 0, 0);
}

// ---------------- fused f32 -> bf16 convert of all 9 tensors ----------------
__global__ __launch_bounds__(256) void cvt_all(
    const float* x, const float* wlq, const float* wlkv, const float* wq,
    const float* wqr, const float* wk, const float* wv, const float* wkr,
    const float* wo, bf16* dx, bf16* dwlq, bf16* dwlkv, bf16* dwq, bf16* dwqr,
    bf16* dwk, bf16* dwv, bf16* dwkr, bf16* dwo) {
  long i = (long)blockIdx.x * 256 + threadIdx.x;
  const float* src;
  bf16* dst;
  long base;
  if (i < 2097152L)      { src = x;    dst = dx;    base = 0; }
  else if (i < 2621440L) { src = wlq;  dst = dwlq;  base = 2097152L; }
  else if (i < 2883584L) { src = wlkv; dst = dwlkv; base = 2621440L; }
  else if (i < 3407872L) { src = wq;   dst = dwq;   base = 2883584L; }
  else if (i < 3932160L) { src = wqr;  dst = dwqr;  base = 3407872L; }
  else if (i < 4194304L) { src = wk;   dst = dwk;   base = 3932160L; }
  else if (i < 4456448L) { src = wv;   dst = dwv;   base = 4194304L; }
  else if (i < 5505024L) { src = wkr;  dst = dwkr;  base = 4456448L; }
  else                   { src = wo;   dst = dwo;   base = 5505024L; }
  long j = i - base;
  float4 f = ((const float4*)src)[j];
  union { ushort4 u4; bf16 h[4]; } cv;
  cv.h[0] = __float2bfloat16(f.x);
  cv.h[1] = __float2bfloat16(f.y);
  cv.h[2] = __float2bfloat16(f.z);
  cv.h[3] = __float2bfloat16(f.w);
  ((ushort4*)dst)[j] = cv.u4;
}

// ---------------- GEMM body: C = A @ B^T, 128x128 tile, BK=64 ----------------
// Epilogue (bf16 modes): every 128x128 C-tile maps to a contiguous 128-col
// row-segment of the target (head-major; n-boundaries are tile-aligned), so
// stage bf16(C) in LDS [128][136] (16B-aligned rows) and store 8x short8/thread.
template <int MODE>
__device__ __forceinline__ void gemm_body(const bf16* __restrict__ A,
                                          const bf16* __restrict__ Bw,
                                          const float* __restrict__ bias,
                                          void* __restrict__ Cout,
                                          void* __restrict__ Cout2,
                                          const float* __restrict__ fco,
                                          const float* __restrict__ fsi,
                                          int M, int N, int K, int lda) {
  extern __shared__ __align__(16) bf16 smem[];  // >= 128*136 bf16
  bf16* As = smem;
  bf16* Bs = smem + 8192;
  const int tid = threadIdx.x;
  const int lane = tid & 63;
  const int w = tid >> 6;
  const int wm = w & 1, wn = w >> 1;
  const int m0 = blockIdx.y * 128, n0 = blockIdx.x * 128;
  const int lr = lane & 15, lg = lane >> 4;

  floatx4 acc[4][4];
#pragma unroll
  for (int mi = 0; mi < 4; ++mi)
#pragma unroll
    for (int ni = 0; ni < 4; ++ni)
#pragma unroll
      for (int r = 0; r < 4; ++r) acc[mi][ni][r] = 0.f;

  for (int k0 = 0; k0 < K; k0 += 64) {
    __syncthreads();
#pragma unroll
    for (int i = 0; i < 4; ++i) {
      int c = i * 256 + tid;
      int row = c >> 3;
      int cg = (c & 7) ^ (row & 7);
      async16(A + (size_t)(m0 + row) * lda + k0 + cg * 8, As + (i * 256 + w * 64) * 8);
      async16(Bw + (size_t)(n0 + row) * K + k0 + cg * 8, Bs + (i * 256 + w * 64) * 8);
    }
    __syncthreads();

#pragma unroll
    for (int ks = 0; ks < 2; ++ks) {
      short8 af[4], bfr[4];
#pragma unroll
      for (int mi = 0; mi < 4; ++mi) {
        int row = wm * 64 + mi * 16 + lr;
        af[mi] = *(const short8*)&As[row * 64 + (((ks * 4 + lg) ^ (lr & 7)) * 8)];
      }
#pragma unroll
      for (int ni = 0; ni < 4; ++ni) {
        int row = wn * 64 + ni * 16 + lr;
        bfr[ni] = *(const short8*)&Bs[row * 64 + (((ks * 4 + lg) ^ (lr & 7)) * 8)];
      }
#pragma unroll
      for (int mi = 0; mi < 4; ++mi)
#pragma unroll
        for (int ni = 0; ni < 4; ++ni)
          acc[mi][ni] = MFMA(af[mi], bfr[ni], acc[mi][ni]);
    }
  }

  const int bb = m0 >> 11, s0 = m0 & 2047;

  if (MODE == 5 && n0 >= 2048) {
    // V-transpose path: stage with 129-stride (scalar column reads), as before.
    __syncthreads();
#pragma unroll
    for (int mi = 0; mi < 4; ++mi)
#pragma unroll
      for (int ni = 0; ni < 4; ++ni)
#pragma unroll
        for (int r = 0; r < 4; ++r) {
          int ml = wm * 64 + mi * 16 + lg * 4 + r;
          int nl = wn * 64 + ni * 16 + lr;
          smem[ml * 129 + nl] = __float2bfloat16(acc[mi][ni][r]);
        }
    __syncthreads();
    int hh = (n0 - 2048) >> 7;
    short* vbase = (short*)Cout2 + ((size_t)(bb * Hh + hh) * 128) * Ss;
#pragma unroll
    for (int pa = 0; pa < 8; ++pa) {
      int d = pa * 16 + (tid >> 4);
      int sc = (tid & 15) * 8;
      short8 v;
#pragma unroll
      for (int i = 0; i < 8; ++i) v[i] = *(const short*)&smem[(sc + i) * 129 + d];
      *(short8*)(vbase + (size_t)d * Ss + s0 + sc) = v;
    }
    return;
  }

  if (MODE == 3) {
    // float output, n-contiguous per 16 lanes: keep direct stores.
#pragma unroll
    for (int mi = 0; mi < 4; ++mi)
#pragma unroll
      for (int ni = 0; ni < 4; ++ni)
#pragma unroll
        for (int r = 0; r < 4; ++r) {
          int m = m0 + wm * 64 + mi * 16 + lg * 4 + r;
          int n = n0 + wn * 64 + ni * 16 + lr;
          ((float*)Cout)[(size_t)m * N + n] = acc[mi][ni][r] + bias[n];
        }
    return;
  }

  // ---- bf16 modes (4/5-direct/6): rope in-register, stage, coalesced store.
  const bool rope = (MODE == 4) ? (n0 >= 2048) : (MODE == 6) ? (n0 >= 1536) : false;
  const int nsub = (MODE == 4) ? 2048 : 1536;

  __syncthreads();  // K-loop LDS reads done before overwrite
#pragma unroll
  for (int mi = 0; mi < 4; ++mi)
#pragma unroll
    for (int ni = 0; ni < 4; ++ni)
#pragma unroll
      for (int r = 0; r < 4; ++r) {
        int ml = wm * 64 + mi * 16 + lg * 4 + r;
        int nl = wn * 64 + ni * 16 + lr;
        float v = acc[mi][ni][r];
        if (rope) {
          int s = s0 + ml;
          v += bias[(n0 - nsub) + nl];
          float vp = __shfl_xor(v, 1, 64);
          float co = fco[s * 64 + (nl >> 1)];
          float sn = fsi[s * 64 + (nl >> 1)];
          v = (nl & 1) ? (v * co + vp * sn) : (v * co - vp * sn);
        }
        smem[ml * 136 + nl] = __float2bfloat16(v);
      }
  __syncthreads();

  // tile -> contiguous dest segment
  short* dst;
  size_t dbase;
  int stride;
  if (MODE == 6 && n0 < 1536) {
    dst = (short*)Cout;
    dbase = (size_t)m0 * 1536 + n0;
    stride = 1536;
  } else if (MODE == 6) {  // kr -> kcat[...][128+d]
    int hh = (n0 - 1536) >> 7;
    dst = (short*)Cout2;
    dbase = ((size_t)(bb * Hh + hh) * Ss + s0) * 256 + 128;
    stride = 256;
  } else if (MODE == 4 && n0 < 2048) {
    int hh = n0 >> 7;
    dst = (short*)Cout;
    dbase = ((size_t)(bb * Hh + hh) * Ss + s0) * 256;
    stride = 256;
  } else if (MODE == 4) {  // qr -> qcat[...][128+d]
    int hh = (n0 - 2048) >> 7;
    dst = (short*)Cout;
    dbase = ((size_t)(bb * Hh + hh) * Ss + s0) * 256 + 128;
    stride = 256;
  } else {  // MODE 5, n0 < 2048 : k -> kcat[...][d]
    int hh = n0 >> 7;
    dst = (short*)Cout;
    dbase = ((size_t)(bb * Hh + hh) * Ss + s0) * 256;
    stride = 256;
  }
#pragma unroll
  for (int i = 0; i < 8; ++i) {
    int c = i * 256 + tid;
    int row = c >> 4, col = (c & 15) * 8;
    short8 vv = *(const short8*)&smem[row * 136 + col];
    *(short8*)(dst + dbase + (size_t)row * stride + col) = vv;
  }
}

template <int MODE>
__global__ __launch_bounds__(256, 4) void gemm_bt(const bf16* __restrict__ A,
                                                  const bf16* __restrict__ Bw,
                                                  const float* __restrict__ bias,
                                                  void* __restrict__ Cout,
                                                  void* __restrict__ Cout2,
                                                  const float* __restrict__ fco,
                                                  const float* __restrict__ fsi,
                                                  int M, int N, int K, int lda) {
  gemm_body<MODE>(A, Bw, bias, Cout, Cout2, fco, fsi, M, N, K, lda);
}

// fused q|qr (z=0) and k|v (z=1) projection GEMMs
__global__ __launch_bounds__(256, 4) void gemm_qkv(const bf16* __restrict__ ccat,
                                                   const bf16* __restrict__ wqcat,
                                                   const bf16* __restrict__ wkvcat,
                                                   const float* __restrict__ bqr,
                                                   void* __restrict__ qcat,
                                                   void* __restrict__ kcat,
                                                   void* __restrict__ vt,
                                                   const float* __restrict__ fco,
                                                   const float* __restrict__ fsi) {
  if (blockIdx.z == 0)
    gemm_body<4>(ccat, wqcat, bqr, qcat, nullptr, fco, fsi, 4096, 4096, 1024, 1536);
  else
    gemm_body<5>(ccat + 1024, wkvcat, nullptr, kcat, vt, nullptr, nullptr, 4096, 4096, 512, 1536);
}

// ---------------- flash attention v9 (unchanged from R12) ----------------
#define FA_STAGE(KSN, VSN, J)                                                    \
  {                                                                              \
    _Pragma("unroll") for (int i = 0; i < 4; ++i) {                              \
      int r = w * 8 + i * 2 + (lane >> 5);                                       \
      async16(Kb + (size_t)((J) + r) * 256 + (((lane & 31) ^ (r & 7)) * 8),      \
              KSN + (w * 8 + i * 2) * 256);                                      \
    }                                                                            \
    _Pragma("unroll") for (int i = 0; i < 2; ++i) {                              \
      int d = w * 32 + i * 16 + (lane >> 2);                                     \
      async16(Vb + (size_t)d * Ss + (J) + (((lane & 3) ^ ((d >> 1) & 3)) * 8),   \
              VSN + (w * 32 + i * 16) * 32);                                     \
    }                                                                            \
  }

#define FA_COMPUTE(KP, VQ)                                                       \
  {                                                                              \
    floatx16 sf;                                                                 \
    _Pragma("unroll") for (int r = 0; r < 16; ++r) sf[r] = 0.f;                  \
    __builtin_amdgcn_s_setprio(1);                                               \
    _Pragma("unroll") for (int dt = 0; dt < 16; ++dt) {                          \
      short8 kf = *(const short8*)(KP[dt & 3] + (dt >> 2) * 64);                 \
      sf = MFMA32(kf, qf[dt], sf);                                               \
    }                                                                            \
    __builtin_amdgcn_s_setprio(0);                                               \
    unsigned pk[8];                                                              \
    _Pragma("unroll") for (int rp = 0; rp < 8; ++rp) {                           \
      float p0 = exp2f(sf[2 * rp] * CE);                                         \
      float p1 = exp2f(sf[2 * rp + 1] * CE);                                     \
      l += p0 + p1;                                                              \
      bf16 b0 = __float2bfloat16(p0);                                            \
      bf16 b1 = __float2bfloat16(p1);                                            \
      pk[rp] = ((unsigned)*(const unsigned short*)&b1 << 16) |                   \
               *(const unsigned short*)&b0;                                      \
    }                                                                            \
    __builtin_amdgcn_s_setprio(1);                                               \
    _Pragma("unroll") for (int kb = 0; kb < 2; ++kb) {                           \
      uintx2 w02 = __builtin_amdgcn_permlane32_swap(pk[kb * 4 + 0],              \
                                                    pk[kb * 4 + 2], false, false); \
      uintx2 w13 = __builtin_amdgcn_permlane32_swap(pk[kb * 4 + 1],              \
                                                    pk[kb * 4 + 3], false, false); \
      union { unsigned u[4]; short8 s; } pa;                                     \
      pa.u[0] = w02.x; pa.u[1] = w13.x; pa.u[2] = w02.y; pa.u[3] = w13.y;        \
      _Pragma("unroll") for (int nb = 0; nb < 4; ++nb) {                         \
        short8 vf = *(const short8*)(VQ[kb] + nb * 1024);                        \
        oacc[nb] = MFMA32(pa.s, vf, oacc[nb]);                                   \
      }                                                                          \
    }                                                                            \
    __builtin_amdgcn_s_setprio(0);                                               \
    __syncthreads();                                                             \
  }

__global__ __launch_bounds__(256, 2) void flash_attn(const bf16* __restrict__ Q,
                                                     const bf16* __restrict__ Kc,
                                                     const bf16* __restrict__ Vt,
                                                     bf16* __restrict__ Oa) {
  const float CE = 0.08838834764831845f * 1.4426950408889634f;  // scale*log2e
  __shared__ __align__(16) bf16 Ks0[32 * 256];  // 16KB
  __shared__ __align__(16) bf16 Ks1[32 * 256];  // 16KB
  __shared__ __align__(16) bf16 Vs0[128 * 32];  // 8KB
  __shared__ __align__(16) bf16 Vs1[128 * 32];  // 8KB

  const int lane = threadIdx.x & 63;
  const int w = threadIdx.x >> 6;
  const int m = lane & 31;   // q column / d column / lds row index
  const int hi = lane >> 5;  // k-slice half
  const int bh = blockIdx.x;
  const int b = bh >> 4, h = bh & 15;
  const int q0 = blockIdx.y * 128 + w * 32;

  const bf16* Qb = Q + (size_t)bh * Ss * 256;
  const bf16* Kb = Kc + (size_t)bh * Ss * 256;
  const bf16* Vb = Vt + (size_t)bh * 128 * Ss;

  // Q fragments (B-operand): lane holds Q[q0+m][dt*16 + hi*8 + j]
  short8 qf[16];
  {
    const short* Qrow = (const short*)Qb + (size_t)(q0 + m) * 256 + hi * 8;
#pragma unroll
    for (int dt = 0; dt < 16; ++dt) qf[dt] = *(const short8*)(Qrow + dt * 16);
  }

  // Loop-invariant LDS read pointers, per buffer (static indexing only).
  const int key = m & 7;
  const int vkey = (m >> 1) & 3;
  const short* kp0[4];
  const short* kp1[4];
#pragma unroll
  for (int dl = 0; dl < 4; ++dl) {
    int off = m * 256 + (((2 * dl + hi) ^ key) * 8);
    kp0[dl] = (const short*)Ks0 + off;
    kp1[dl] = (const short*)Ks1 + off;
  }
  const short* vq0[2];
  const short* vq1[2];
#pragma unroll
  for (int kb = 0; kb < 2; ++kb) {
    int off = m * 32 + (((2 * kb + hi) ^ vkey) * 8);
    vq0[kb] = (const short*)Vs0 + off;
    vq1[kb] = (const short*)Vs1 + off;
  }

  float l = 0.f;
  floatx16 oacc[4];
#pragma unroll
  for (int nb = 0; nb < 4; ++nb)
#pragma unroll
    for (int r = 0; r < 16; ++r) oacc[nb][r] = 0.f;

  FA_STAGE(Ks0, Vs0, 0);
  __syncthreads();

#pragma unroll 1
  for (int g = 0; g < 64; g += 2) {
    // body A: stage tile g+1 into buf1, compute tile g from buf0
    FA_STAGE(Ks1, Vs1, (g + 1) * 32);
    FA_COMPUTE(kp0, vq0);
    // body B: stage tile g+2 into buf0 (guarded), compute tile g+1 from buf1
    int jn = (g + 2) * 32;
    if (jn < Ss) FA_STAGE(Ks0, Vs0, jn);
    FA_COMPUTE(kp1, vq1);
  }

  // total l for q = q0+m (both halves hold partials over disjoint k)
  float lsum = l + __shfl_xor(l, 32, 64);
  float inv = 1.f / lsum;

#pragma unroll
  for (int r = 0; r < 16; ++r) {
    int qr = (r & 3) + 8 * (r >> 2) + 4 * hi;        // O row (q-local)
    float invr = __shfl(inv, (lane & 32) + qr, 64);  // inv of that q
    int s = q0 + qr;
#pragma unroll
    for (int nb = 0; nb < 4; ++nb) {
      int d = nb * 32 + m;
      Oa[((size_t)(b * Ss + s)) * (Hh * 128) + h * 128 + d] =
          __float2bfloat16(oacc[nb][r] * invr);
    }
  }
}

// ---------------- host ----------------
extern "C" void kernel_launch(void* const* d_in, const int* in_sizes, int n_in,
                              void* d_out, int out_size, void* d_ws, size_t ws_size,
                              hipStream_t stream) {
  const float* x    = (const float*)d_in[0];
  const float* fco  = (const float*)d_in[1];
  const float* fsi  = (const float*)d_in[2];
  const float* wlq  = (const float*)d_in[3];
  const float* wlkv = (const float*)d_in[4];
  const float* wq   = (const float*)d_in[5];
  const float* wk   = (const float*)d_in[6];
  const float* wv   = (const float*)d_in[7];
  const float* wqr  = (const float*)d_in[8];
  const float* bqr  = (const float*)d_in[9];
  const float* wkr  = (const float*)d_in[10];
  const float* bkr  = (const float*)d_in[11];
  const float* wo   = (const float*)d_in[12];
  const float* bo   = (const float*)d_in[13];

  char* ws = (char*)d_ws;
  size_t o = 0;
  bf16* x_b    = (bf16*)(ws + o); o += (size_t)Bb * Ss * DIMd * 2;
  bf16* wbig   = (bf16*)(ws + o); o += (size_t)3584 * 2048 * 2;   // [wlq;wlkv;wkr]
  bf16* wqcat  = (bf16*)(ws + o); o += (size_t)4096 * 1024 * 2;   // [wq;wqr]
  bf16* wkvcat = (bf16*)(ws + o); o += (size_t)4096 * 512 * 2;    // [wk;wv]
  bf16* wo_b   = (bf16*)(ws + o); o += (size_t)2048 * 2048 * 2;
  bf16* ccat   = (bf16*)(ws + o); o += (size_t)4096 * 1536 * 2;   // [cq|ckv]
  bf16* qcat   = (bf16*)(ws + o); o += (size_t)Bb * Hh * Ss * 256 * 2;
  bf16* kcat   = (bf16*)(ws + o); o += (size_t)Bb * Hh * Ss * 256 * 2;
  bf16* vt     = (bf16*)(ws + o); o += (size_t)Bb * Hh * 128 * Ss * 2;
  bf16* attn   = (bf16*)(ws + o); o += (size_t)4096 * 2048 * 2;

  cvt_all<<<25600, 256, 0, stream>>>(
      x, wlq, wlkv, wq, wqr, wk, wv, wkr, wo,
      x_b,
      wbig,
      wbig + (size_t)1024 * 2048,
      wqcat,
      wqcat + (size_t)2048 * 1024,
      wkvcat,
      wkvcat + (size_t)2048 * 512,
      wbig + (size_t)1536 * 2048,
      wo_b);

  const int M = Bb * Ss;  // 4096
  const int GEMM_LDS = 128 * 136 * 2;  // 34816B: staging 32KB, epilogue 34KB
  gemm_bt<6><<<dim3(28, 32), 256, GEMM_LDS, stream>>>(
      x_b, wbig, bkr, ccat, kcat, fco, fsi, M, 3584, 2048, 2048);
  gemm_qkv<<<dim3(32, 32, 2), 256, GEMM_LDS, stream>>>(
      ccat, wqcat, wkvcat, bqr, qcat, kcat, vt, fco, fsi);

  flash_attn<<<dim3(Bb * Hh, Ss / 128), 256, 0, stream>>>(qcat, kcat, vt, attn);

  gemm_bt<3><<<dim3(16, 32), 256, GEMM_LDS, stream>>>(
      attn, wo_b, bo, (float*)d_out, nullptr, nullptr, nullptr, M, 2048, 2048, 2048);
}

// Round 5
// 446.220 us; speedup vs baseline: 1.1135x; 1.0464x over previous
//
#include <hip/hip_runtime.h>
#include <hip/hip_bf16.h>

// MLA forward, bf16-MFMA pipeline. B=2 S=2048 DIM=2048 H=16 DH=128 LQ=1024 LKV=512
// R15: (1) revert R14 epilogue (LDS-staged stores were -12us: writes were never
// the bound). (2) flash v10 — 3-slot LDS ring (72KB, occupancy unchanged: LDS
// caps at 2 blocks/CU), pk carried across bodies (T15), ONE s_barrier per body
// with counted vmcnt(6) (never 0 in steady state), stage issued into the slot
// freed 2 bodies ago. (3) softmax scale*log2e folded into q-projection GEMM
// epilogue (removes 16 v_mul/iter in flash).

#define Bb 2
#define Ss 2048
#define DIMd 2048
#define Hh 16
#define DHd 128

typedef __hip_bfloat16 bf16;
typedef __attribute__((ext_vector_type(8))) short short8;
typedef __attribute__((ext_vector_type(4))) float floatx4;
typedef __attribute__((ext_vector_type(16))) float floatx16;
typedef __attribute__((ext_vector_type(2))) unsigned int uintx2;

#define MFMA(a, b, c) __builtin_amdgcn_mfma_f32_16x16x32_bf16((a), (b), (c), 0, 0, 0)
#define MFMA32(a, b, c) __builtin_amdgcn_mfma_f32_32x32x16_bf16((a), (b), (c), 0, 0, 0)

// scale (1/sqrt(128)) * log2(e): applied to q in the projection GEMM epilogue.
#define CEF (0.08838834764831845f * 1.4426950408889634f)

__device__ __forceinline__ void async16(const bf16* g, bf16* l) {
  __builtin_amdgcn_global_load_lds(
      (const __attribute__((address_space(1))) unsigned int*)g,
      (__attribute__((address_space(3))) unsigned int*)l, 16, 0, 0);
}

// ---------------- fused f32 -> bf16 convert of all 9 tensors ----------------
__global__ __launch_bounds__(256) void cvt_all(
    const float* x, const float* wlq, const float* wlkv, const float* wq,
    const float* wqr, const float* wk, const float* wv, const float* wkr,
    const float* wo, bf16* dx, bf16* dwlq, bf16* dwlkv, bf16* dwq, bf16* dwqr,
    bf16* dwk, bf16* dwv, bf16* dwkr, bf16* dwo) {
  long i = (long)blockIdx.x * 256 + threadIdx.x;
  const float* src;
  bf16* dst;
  long base;
  if (i < 2097152L)      { src = x;    dst = dx;    base = 0; }
  else if (i < 2621440L) { src = wlq;  dst = dwlq;  base = 2097152L; }
  else if (i < 2883584L) { src = wlkv; dst = dwlkv; base = 2621440L; }
  else if (i < 3407872L) { src = wq;   dst = dwq;   base = 2883584L; }
  else if (i < 3932160L) { src = wqr;  dst = dwqr;  base = 3407872L; }
  else if (i < 4194304L) { src = wk;   dst = dwk;   base = 3932160L; }
  else if (i < 4456448L) { src = wv;   dst = dwv;   base = 4194304L; }
  else if (i < 5505024L) { src = wkr;  dst = dwkr;  base = 4456448L; }
  else                   { src = wo;   dst = dwo;   base = 5505024L; }
  long j = i - base;
  float4 f = ((const float4*)src)[j];
  union { ushort4 u4; bf16 h[4]; } cv;
  cv.h[0] = __float2bfloat16(f.x);
  cv.h[1] = __float2bfloat16(f.y);
  cv.h[2] = __float2bfloat16(f.z);
  cv.h[3] = __float2bfloat16(f.w);
  ((ushort4*)dst)[j] = cv.u4;
}

// ---------------- GEMM body: C = A @ B^T, 128x128 tile, BK=64 ----------------
template <int MODE>
__device__ __forceinline__ void gemm_body(const bf16* __restrict__ A,
                                          const bf16* __restrict__ Bw,
                                          const float* __restrict__ bias,
                                          void* __restrict__ Cout,
                                          void* __restrict__ Cout2,
                                          const float* __restrict__ fco,
                                          const float* __restrict__ fsi,
                                          int M, int N, int K, int lda) {
  extern __shared__ __align__(16) bf16 smem[];  // 128*129
  bf16* As = smem;
  bf16* Bs = smem + 8192;
  const int tid = threadIdx.x;
  const int lane = tid & 63;
  const int w = tid >> 6;
  const int wm = w & 1, wn = w >> 1;
  const int m0 = blockIdx.y * 128, n0 = blockIdx.x * 128;
  const int lr = lane & 15, lg = lane >> 4;

  floatx4 acc[4][4];
#pragma unroll
  for (int mi = 0; mi < 4; ++mi)
#pragma unroll
    for (int ni = 0; ni < 4; ++ni)
#pragma unroll
      for (int r = 0; r < 4; ++r) acc[mi][ni][r] = 0.f;

  for (int k0 = 0; k0 < K; k0 += 64) {
    __syncthreads();
#pragma unroll
    for (int i = 0; i < 4; ++i) {
      int c = i * 256 + tid;
      int row = c >> 3;
      int cg = (c & 7) ^ (row & 7);
      async16(A + (size_t)(m0 + row) * lda + k0 + cg * 8, As + (i * 256 + w * 64) * 8);
      async16(Bw + (size_t)(n0 + row) * K + k0 + cg * 8, Bs + (i * 256 + w * 64) * 8);
    }
    __syncthreads();

#pragma unroll
    for (int ks = 0; ks < 2; ++ks) {
      short8 af[4], bfr[4];
#pragma unroll
      for (int mi = 0; mi < 4; ++mi) {
        int row = wm * 64 + mi * 16 + lr;
        af[mi] = *(const short8*)&As[row * 64 + (((ks * 4 + lg) ^ (lr & 7)) * 8)];
      }
#pragma unroll
      for (int ni = 0; ni < 4; ++ni) {
        int row = wn * 64 + ni * 16 + lr;
        bfr[ni] = *(const short8*)&Bs[row * 64 + (((ks * 4 + lg) ^ (lr & 7)) * 8)];
      }
#pragma unroll
      for (int mi = 0; mi < 4; ++mi)
#pragma unroll
        for (int ni = 0; ni < 4; ++ni)
          acc[mi][ni] = MFMA(af[mi], bfr[ni], acc[mi][ni]);
    }
  }

  if (MODE == 5 && n0 >= 2048) {
    __syncthreads();
#pragma unroll
    for (int mi = 0; mi < 4; ++mi)
#pragma unroll
      for (int ni = 0; ni < 4; ++ni)
#pragma unroll
        for (int r = 0; r < 4; ++r) {
          int ml = wm * 64 + mi * 16 + lg * 4 + r;
          int nl = wn * 64 + ni * 16 + lr;
          smem[ml * 129 + nl] = __float2bfloat16(acc[mi][ni][r]);
        }
    __syncthreads();
    int bb = m0 >> 11, s0 = m0 & 2047;
    int hh = (n0 - 2048) >> 7;
    short* vbase = (short*)Cout2 + ((size_t)(bb * Hh + hh) * 128) * Ss;
#pragma unroll
    for (int pa = 0; pa < 8; ++pa) {
      int d = pa * 16 + (tid >> 4);
      int sc = (tid & 15) * 8;
      short8 v;
#pragma unroll
      for (int i = 0; i < 8; ++i) v[i] = *(const short*)&smem[(sc + i) * 129 + d];
      *(short8*)(vbase + (size_t)d * Ss + s0 + sc) = v;
    }
    return;
  }

#pragma unroll
  for (int mi = 0; mi < 4; ++mi)
#pragma unroll
    for (int ni = 0; ni < 4; ++ni)
#pragma unroll
      for (int r = 0; r < 4; ++r) {
        int m = m0 + wm * 64 + mi * 16 + lg * 4 + r;
        int n = n0 + wn * 64 + ni * 16 + lr;
        float v = acc[mi][ni][r];
        int bb = m >> 11, s = m & 2047;
        if (MODE == 3) {
          v += bias[n];
          ((float*)Cout)[(size_t)m * N + n] = v;
        } else if (MODE == 4) {
          // q|qr: fold softmax scale*log2e into q (flash then uses exp2 direct)
          if (n < 2048) {
            int hh = n >> 7, d = n & 127;
            ((bf16*)Cout)[((size_t)((bb * Hh + hh) * Ss + s)) * 256 + d] =
                __float2bfloat16(v * CEF);
          } else {
            int n2 = n - 2048;
            int hh = n2 >> 7, d = n2 & 127;
            v += bias[n2];
            float vp = __shfl_xor(v, 1, 64);
            float co = fco[s * 64 + (d >> 1)];
            float sn = fsi[s * 64 + (d >> 1)];
            v = (d & 1) ? (v * co + vp * sn) : (v * co - vp * sn);
            ((bf16*)Cout)[((size_t)((bb * Hh + hh) * Ss + s)) * 256 + 128 + d] =
                __float2bfloat16(v * CEF);
          }
        } else if (MODE == 5) {
          int hh = n >> 7, d = n & 127;
          ((bf16*)Cout)[((size_t)((bb * Hh + hh) * Ss + s)) * 256 + d] =
              __float2bfloat16(v);
        } else if (MODE == 6) {
          if (n < 1536) {
            ((bf16*)Cout)[(size_t)m * 1536 + n] = __float2bfloat16(v);
          } else {
            int n2 = n - 1536;
            int hh = n2 >> 7, d = n2 & 127;
            v += bias[n2];
            float vp = __shfl_xor(v, 1, 64);
            float co = fco[s * 64 + (d >> 1)];
            float sn = fsi[s * 64 + (d >> 1)];
            v = (d & 1) ? (v * co + vp * sn) : (v * co - vp * sn);
            ((bf16*)Cout2)[((size_t)((bb * Hh + hh) * Ss + s)) * 256 + 128 + d] =
                __float2bfloat16(v);
          }
        }
      }
}

template <int MODE>
__global__ __launch_bounds__(256, 4) void gemm_bt(const bf16* __restrict__ A,
                                                  const bf16* __restrict__ Bw,
                                                  const float* __restrict__ bias,
                                                  void* __restrict__ Cout,
                                                  void* __restrict__ Cout2,
                                                  const float* __restrict__ fco,
                                                  const float* __restrict__ fsi,
                                                  int M, int N, int K, int lda) {
  gemm_body<MODE>(A, Bw, bias, Cout, Cout2, fco, fsi, M, N, K, lda);
}

// fused q|qr (z=0) and k|v (z=1) projection GEMMs
__global__ __launch_bounds__(256, 4) void gemm_qkv(const bf16* __restrict__ ccat,
                                                   const bf16* __restrict__ wqcat,
                                                   const bf16* __restrict__ wkvcat,
                                                   const float* __restrict__ bqr,
                                                   void* __restrict__ qcat,
                                                   void* __restrict__ kcat,
                                                   void* __restrict__ vt,
                                                   const float* __restrict__ fco,
                                                   const float* __restrict__ fsi) {
  if (blockIdx.z == 0)
    gemm_body<4>(ccat, wqcat, bqr, qcat, nullptr, fco, fsi, 4096, 4096, 1024, 1536);
  else
    gemm_body<5>(ccat + 1024, wkvcat, nullptr, kcat, vt, nullptr, nullptr, 4096, 4096, 512, 1536);
}

// ---------------- flash attention v10 ----------------
// grid(B*H, S/128), 4 waves, 32 q-rows/wave (32x32x16, swapped QK^T).
// 3-slot LDS ring (24KB/slot = 72KB). pk (packed P of tile g) carried across
// bodies. Body g: [stage g+2 -> slot (g+2)%3 (freed: last read was PV(g-1),
// before body g-1's barrier)] [PV(g) <- pk] [vmcnt(6)+s_barrier: stage(g+1)
// landed across all waves, stage(g+2) still in flight] [QK^T(g+1)] [sm->pk].
#define FA_STAGE(KSN, VSN, J)                                                    \
  {                                                                              \
    _Pragma("unroll") for (int i = 0; i < 4; ++i) {                              \
      int r = w * 8 + i * 2 + (lane >> 5);                                       \
      async16(Kb + (size_t)((J) + r) * 256 + (((lane & 31) ^ (r & 7)) * 8),      \
              KSN + (w * 8 + i * 2) * 256);                                      \
    }                                                                            \
    _Pragma("unroll") for (int i = 0; i < 2; ++i) {                              \
      int d = w * 32 + i * 16 + (lane >> 2);                                     \
      async16(Vb + (size_t)d * Ss + (J) + (((lane & 3) ^ ((d >> 1) & 3)) * 8),   \
              VSN + (w * 32 + i * 16) * 32);                                     \
    }                                                                            \
  }

#define FA_QKT(KP)                                                               \
  {                                                                              \
    _Pragma("unroll") for (int r = 0; r < 16; ++r) sf[r] = 0.f;                  \
    __builtin_amdgcn_s_setprio(1);                                               \
    _Pragma("unroll") for (int dt = 0; dt < 16; ++dt) {                          \
      short8 kf = *(const short8*)(KP[dt & 3] + (dt >> 2) * 64);                 \
      sf = MFMA32(kf, qf[dt], sf);                                               \
    }                                                                            \
    __builtin_amdgcn_s_setprio(0);                                               \
  }

#define FA_SM()                                                                  \
  {                                                                              \
    _Pragma("unroll") for (int rp = 0; rp < 8; ++rp) {                           \
      float p0 = exp2f(sf[2 * rp]);                                              \
      float p1 = exp2f(sf[2 * rp + 1]);                                          \
      l += p0 + p1;                                                              \
      bf16 b0 = __float2bfloat16(p0);                                            \
      bf16 b1 = __float2bfloat16(p1);                                            \
      pk[rp] = ((unsigned)*(const unsigned short*)&b1 << 16) |                   \
               *(const unsigned short*)&b0;                                      \
    }                                                                            \
  }

#define FA_PV(VQ)                                                                \
  {                                                                              \
    __builtin_amdgcn_s_setprio(1);                                               \
    _Pragma("unroll") for (int kb = 0; kb < 2; ++kb) {                           \
      uintx2 w02 = __builtin_amdgcn_permlane32_swap(pk[kb * 4 + 0],              \
                                                    pk[kb * 4 + 2], false, false); \
      uintx2 w13 = __builtin_amdgcn_permlane32_swap(pk[kb * 4 + 1],              \
                                                    pk[kb * 4 + 3], false, false); \
      union { unsigned u[4]; short8 s; } pa;                                     \
      pa.u[0] = w02.x; pa.u[1] = w13.x; pa.u[2] = w02.y; pa.u[3] = w13.y;        \
      _Pragma("unroll") for (int nb = 0; nb < 4; ++nb) {                         \
        short8 vf = *(const short8*)(VQ[kb] + nb * 1024);                        \
        oacc[nb] = MFMA32(pa.s, vf, oacc[nb]);                                   \
      }                                                                          \
    }                                                                            \
    __builtin_amdgcn_s_setprio(0);                                               \
  }

#define FA_BODY(VQpv, KPqk, KSst, VSst, Jst)                                     \
  FA_STAGE(KSst, VSst, Jst);                                                     \
  FA_PV(VQpv);                                                                   \
  asm volatile("s_waitcnt vmcnt(6)" ::: "memory");                               \
  __builtin_amdgcn_s_barrier();                                                  \
  FA_QKT(KPqk);                                                                  \
  FA_SM();

__global__ __launch_bounds__(256, 2) void flash_attn(const bf16* __restrict__ Q,
                                                     const bf16* __restrict__ Kc,
                                                     const bf16* __restrict__ Vt,
                                                     bf16* __restrict__ Oa) {
  __shared__ __align__(16) bf16 Ks0[32 * 256];  // 16KB
  __shared__ __align__(16) bf16 Ks1[32 * 256];
  __shared__ __align__(16) bf16 Ks2[32 * 256];
  __shared__ __align__(16) bf16 Vs0[128 * 32];  // 8KB
  __shared__ __align__(16) bf16 Vs1[128 * 32];
  __shared__ __align__(16) bf16 Vs2[128 * 32];  // total 72KB -> 2 blocks/CU

  const int lane = threadIdx.x & 63;
  const int w = threadIdx.x >> 6;
  const int m = lane & 31;   // q column / d column / lds row index
  const int hi = lane >> 5;  // k-slice half
  const int bh = blockIdx.x;
  const int b = bh >> 4, h = bh & 15;
  const int q0 = blockIdx.y * 128 + w * 32;

  const bf16* Qb = Q + (size_t)bh * Ss * 256;
  const bf16* Kb = Kc + (size_t)bh * Ss * 256;
  const bf16* Vb = Vt + (size_t)bh * 128 * Ss;

  // Q fragments (B-operand): lane holds Q[q0+m][dt*16 + hi*8 + j]; q is
  // pre-scaled by scale*log2e in the projection GEMM.
  short8 qf[16];
  {
    const short* Qrow = (const short*)Qb + (size_t)(q0 + m) * 256 + hi * 8;
#pragma unroll
    for (int dt = 0; dt < 16; ++dt) qf[dt] = *(const short8*)(Qrow + dt * 16);
  }

  // Loop-invariant LDS read pointers per slot (static indexing only).
  const int key = m & 7;
  const int vkey = (m >> 1) & 3;
  const short *kp0[4], *kp1[4], *kp2[4];
#pragma unroll
  for (int dl = 0; dl < 4; ++dl) {
    int off = m * 256 + (((2 * dl + hi) ^ key) * 8);
    kp0[dl] = (const short*)Ks0 + off;
    kp1[dl] = (const short*)Ks1 + off;
    kp2[dl] = (const short*)Ks2 + off;
  }
  const short *vq0[2], *vq1[2], *vq2[2];
#pragma unroll
  for (int kb = 0; kb < 2; ++kb) {
    int off = m * 32 + (((2 * kb + hi) ^ vkey) * 8);
    vq0[kb] = (const short*)Vs0 + off;
    vq1[kb] = (const short*)Vs1 + off;
    vq2[kb] = (const short*)Vs2 + off;
  }

  float l = 0.f;
  floatx16 sf;
  unsigned pk[8];
  floatx16 oacc[4];
#pragma unroll
  for (int nb = 0; nb < 4; ++nb)
#pragma unroll
    for (int r = 0; r < 16; ++r) oacc[nb][r] = 0.f;

  // prologue: tiles 0,1 staged; QK^T(0)+sm(0)
  FA_STAGE(Ks0, Vs0, 0);
  FA_STAGE(Ks1, Vs1, 32);
  asm volatile("s_waitcnt vmcnt(6)" ::: "memory");  // tile 0 landed
  __builtin_amdgcn_s_barrier();
  FA_QKT(kp0);
  FA_SM();

  // bodies g = 0..59 (20 chunks x 3, slots rotate 0,1,2)
#pragma unroll 1
  for (int c = 0; c < 20; ++c) {
    const int j2 = (3 * c + 2) * 32;
    FA_BODY(vq0, kp1, Ks2, Vs2, j2);          // g=3c
    FA_BODY(vq1, kp2, Ks0, Vs0, j2 + 32);     // g=3c+1
    FA_BODY(vq2, kp0, Ks1, Vs1, j2 + 64);     // g=3c+2
  }
  // g=60, 61
  FA_BODY(vq0, kp1, Ks2, Vs2, 62 * 32);
  FA_BODY(vq1, kp2, Ks0, Vs0, 63 * 32);
  // g=62: no stage left; drain to 0
  FA_PV(vq2);
  asm volatile("s_waitcnt vmcnt(0)" ::: "memory");
  __builtin_amdgcn_s_barrier();
  FA_QKT(kp0);
  FA_SM();
  // final PV(63) (slot 0, already landed)
  FA_PV(vq0);

  // total l for q = q0+m (both halves hold partials over disjoint k)
  float lsum = l + __shfl_xor(l, 32, 64);
  float inv = 1.f / lsum;

#pragma unroll
  for (int r = 0; r < 16; ++r) {
    int qr = (r & 3) + 8 * (r >> 2) + 4 * hi;        // O row (q-local)
    float invr = __shfl(inv, (lane & 32) + qr, 64);  // inv of that q
    int s = q0 + qr;
#pragma unroll
    for (int nb = 0; nb < 4; ++nb) {
      int d = nb * 32 + m;
      Oa[((size_t)(b * Ss + s)) * (Hh * 128) + h * 128 + d] =
          __float2bfloat16(oacc[nb][r] * invr);
    }
  }
}

// ---------------- host ----------------
extern "C" void kernel_launch(void* const* d_in, const int* in_sizes, int n_in,
                              void* d_out, int out_size, void* d_ws, size_t ws_size,
                              hipStream_t stream) {
  const float* x    = (const float*)d_in[0];
  const float* fco  = (const float*)d_in[1];
  const float* fsi  = (const float*)d_in[2];
  const float* wlq  = (const float*)d_in[3];
  const float* wlkv = (const float*)d_in[4];
  const float* wq   = (const float*)d_in[5];
  const float* wk   = (const float*)d_in[6];
  const float* wv   = (const float*)d_in[7];
  const float* wqr  = (const float*)d_in[8];
  const float* bqr  = (const float*)d_in[9];
  const float* wkr  = (const float*)d_in[10];
  const float* bkr  = (const float*)d_in[11];
  const float* wo   = (const float*)d_in[12];
  const float* bo   = (const float*)d_in[13];

  char* ws = (char*)d_ws;
  size_t o = 0;
  bf16* x_b    = (bf16*)(ws + o); o += (size_t)Bb * Ss * DIMd * 2;
  bf16* wbig   = (bf16*)(ws + o); o += (size_t)3584 * 2048 * 2;   // [wlq;wlkv;wkr]
  bf16* wqcat  = (bf16*)(ws + o); o += (size_t)4096 * 1024 * 2;   // [wq;wqr]
  bf16* wkvcat = (bf16*)(ws + o); o += (size_t)4096 * 512 * 2;    // [wk;wv]
  bf16* wo_b   = (bf16*)(ws + o); o += (size_t)2048 * 2048 * 2;
  bf16* ccat   = (bf16*)(ws + o); o += (size_t)4096 * 1536 * 2;   // [cq|ckv]
  bf16* qcat   = (bf16*)(ws + o); o += (size_t)Bb * Hh * Ss * 256 * 2;
  bf16* kcat   = (bf16*)(ws + o); o += (size_t)Bb * Hh * Ss * 256 * 2;
  bf16* vt     = (bf16*)(ws + o); o += (size_t)Bb * Hh * 128 * Ss * 2;
  bf16* attn   = (bf16*)(ws + o); o += (size_t)4096 * 2048 * 2;

  cvt_all<<<25600, 256, 0, stream>>>(
      x, wlq, wlkv, wq, wqr, wk, wv, wkr, wo,
      x_b,
      wbig,
      wbig + (size_t)1024 * 2048,
      wqcat,
      wqcat + (size_t)2048 * 1024,
      wkvcat,
      wkvcat + (size_t)2048 * 512,
      wbig + (size_t)1536 * 2048,
      wo_b);

  const int M = Bb * Ss;  // 4096
  const int GEMM_LDS = 128 * 129 * 2;
  gemm_bt<6><<<dim3(28, 32), 256, GEMM_LDS, stream>>>(
      x_b, wbig, bkr, ccat, kcat, fco, fsi, M, 3584, 2048, 2048);
  gemm_qkv<<<dim3(32, 32, 2), 256, GEMM_LDS, stream>>>(
      ccat, wqcat, wkvcat, bqr, qcat, kcat, vt, fco, fsi);

  flash_attn<<<dim3(Bb * Hh, Ss / 128), 256, 0, stream>>>(qcat, kcat, vt, attn);

  gemm_bt<3><<<dim3(16, 32), 256, GEMM_LDS, stream>>>(
      attn, wo_b, bo, (float*)d_out, nullptr, nullptr, nullptr, M, 2048, 2048, 2048);
}